// Round 1
// baseline (366.183 us; speedup 1.0000x reference)
//
#include <hip/hip_runtime.h>

#define N_NODES 50000
#define N_EDGES 800000

#define SCAN_CHUNK 256
#define SCAN_BLOCKS ((N_NODES + SCAN_CHUNK - 1) / SCAN_CHUNK) // 196

static inline size_t alignUp(size_t x, size_t a) { return (x + a - 1) & ~(a - 1); }

// ---------------- CSR build ----------------

__global__ void k_zero_i32(int* __restrict__ p, int n) {
    int i = blockIdx.x * 256 + threadIdx.x;
    if (i < n) p[i] = 0;
}

__global__ void k_count(const int* __restrict__ row, int* __restrict__ count) {
    int e = blockIdx.x * 256 + threadIdx.x;
    if (e < N_EDGES) atomicAdd(&count[row[e]], 1);
}

__global__ void k_blocksum(const int* __restrict__ count, int* __restrict__ bsum) {
    __shared__ int s[256];
    int t = threadIdx.x;
    int i = blockIdx.x * 256 + t;
    int v = (i < N_NODES) ? count[i] : 0;
    s[t] = v;
    __syncthreads();
    for (int off = 128; off > 0; off >>= 1) {
        if (t < off) s[t] += s[t + off];
        __syncthreads();
    }
    if (t == 0) bsum[blockIdx.x] = s[0];
}

__global__ void k_scan_bsum(int* __restrict__ bsum) {
    __shared__ int s[256];
    int t = threadIdx.x;
    int v = (t < SCAN_BLOCKS) ? bsum[t] : 0;
    s[t] = v;
    __syncthreads();
    for (int off = 1; off < 256; off <<= 1) {
        int add = (t >= off) ? s[t - off] : 0;
        __syncthreads();
        s[t] += add;
        __syncthreads();
    }
    if (t < SCAN_BLOCKS) bsum[t] = s[t] - v; // exclusive
}

__global__ void k_scan_final(const int* __restrict__ count, const int* __restrict__ bsum,
                             int* __restrict__ offsets, int* __restrict__ cursor,
                             float* __restrict__ dinv) {
    __shared__ int s[256];
    int t = threadIdx.x;
    int i = blockIdx.x * 256 + t;
    int v = (i < N_NODES) ? count[i] : 0;
    s[t] = v;
    __syncthreads();
    for (int off = 1; off < 256; off <<= 1) {
        int add = (t >= off) ? s[t - off] : 0;
        __syncthreads();
        s[t] += add;
        __syncthreads();
    }
    if (i < N_NODES) {
        int excl = s[t] - v + bsum[blockIdx.x];
        offsets[i] = excl;
        cursor[i]  = excl;
        dinv[i]    = rsqrtf((float)(v + 1)); // +1 for self-loop; always > 0
    }
}

__global__ void k_scatter(const int* __restrict__ row, const int* __restrict__ col,
                          int* __restrict__ cursor, int* __restrict__ csr_col) {
    int e = blockIdx.x * 256 + threadIdx.x;
    if (e < N_EDGES) {
        int r = row[e];
        int pos = atomicAdd(&cursor[r], 1);
        csr_col[pos] = col[e];
    }
}

// ---------------- Aggregation: out[i] = dinv_i*(dinv_i*h[i] + sum_c dinv_c*h[c]) (+bias) ----

template <int F, bool BIAS>
__global__ void k_aggregate(const float* __restrict__ h, float* __restrict__ out,
                            const int* __restrict__ csr_col, const int* __restrict__ offsets,
                            const int* __restrict__ count, const float* __restrict__ dinv,
                            const float* __restrict__ bias) {
    constexpr int NPB = 256 / F; // nodes per block
    int node = blockIdx.x * NPB + threadIdx.x / F;
    int f = threadIdx.x % F;
    if (node >= N_NODES) return;

    float di = dinv[node];
    float acc0 = di * h[(size_t)node * F + f]; // self-loop term (dinv_i applied again at end)
    float acc1 = 0.f;

    int start = offsets[node];
    int n = count[node];
    const int* cp = csr_col + start;

    int e = 0;
    for (; e + 1 < n; e += 2) {
        int c0 = cp[e];
        int c1 = cp[e + 1];
        acc0 += dinv[c0] * h[(size_t)c0 * F + f];
        acc1 += dinv[c1] * h[(size_t)c1 * F + f];
    }
    if (e < n) {
        int c = cp[e];
        acc0 += dinv[c] * h[(size_t)c * F + f];
    }
    float r = di * (acc0 + acc1);
    if (BIAS) r += bias[f];
    out[(size_t)node * F + f] = r;
}

// ---------------- Small-K fp32 GEMM: out[n, c] = relu(x[n,:] @ W[:, c] + b[c]) ----------------
// BM=64 rows per block; thread micro-tile 4 rows x 8 cols.

template <int K, int NOUT, bool RELU, bool BIAS>
__global__ void k_gemm(const float* __restrict__ x, const float* __restrict__ W,
                       const float* __restrict__ bias, float* __restrict__ out, int nrows) {
    constexpr int BM = 64;
    constexpr int NT = 16 * (NOUT / 8);  // 256 for NOUT=128, 128 for NOUT=64
    constexpr int XS = 68;               // padded stride (16B-aligned, breaks pow2 banks)
    __shared__ float xt[32 * XS];        // x tile transposed: [k][row]
    __shared__ float wt[32 * NOUT];      // W tile: [k][c]

    int tid = threadIdx.x;
    int rg = tid & 15;   // row group: rows rg*4 .. rg*4+3
    int cg = tid >> 4;   // col group: cols cg*8 .. cg*8+7
    int row0 = blockIdx.x * BM;

    float acc[4][8] = {};

    for (int kk = 0; kk < K; kk += 32) {
        __syncthreads();
        // load x tile (64 rows x 32 k), transpose into LDS
        constexpr int XF4 = 64 * 32 / 4; // 512 float4s
        for (int i = tid; i < XF4; i += NT) {
            int r = i >> 3;
            int kc = (i & 7) * 4;
            int grow = row0 + r;
            float4 v = make_float4(0.f, 0.f, 0.f, 0.f);
            if (grow < nrows)
                v = *reinterpret_cast<const float4*>(&x[(size_t)grow * K + kk + kc]);
            xt[(kc + 0) * XS + r] = v.x;
            xt[(kc + 1) * XS + r] = v.y;
            xt[(kc + 2) * XS + r] = v.z;
            xt[(kc + 3) * XS + r] = v.w;
        }
        // load W tile (32 k x NOUT)
        constexpr int WF4 = 32 * NOUT / 4;
        for (int i = tid; i < WF4; i += NT) {
            int k = i / (NOUT / 4);
            int c = (i % (NOUT / 4)) * 4;
            *reinterpret_cast<float4*>(&wt[k * NOUT + c]) =
                *reinterpret_cast<const float4*>(&W[(size_t)(kk + k) * NOUT + c]);
        }
        __syncthreads();

#pragma unroll 8
        for (int k = 0; k < 32; k++) {
            float4 xv = *reinterpret_cast<const float4*>(&xt[k * XS + rg * 4]);
            float4 w0 = *reinterpret_cast<const float4*>(&wt[k * NOUT + cg * 8]);
            float4 w1 = *reinterpret_cast<const float4*>(&wt[k * NOUT + cg * 8 + 4]);
            float xr[4] = {xv.x, xv.y, xv.z, xv.w};
            float wr[8] = {w0.x, w0.y, w0.z, w0.w, w1.x, w1.y, w1.z, w1.w};
#pragma unroll
            for (int a = 0; a < 4; a++)
#pragma unroll
                for (int b = 0; b < 8; b++) acc[a][b] += xr[a] * wr[b];
        }
    }

    float bv[8];
    if (BIAS) {
#pragma unroll
        for (int b = 0; b < 8; b++) bv[b] = bias[cg * 8 + b];
    }
#pragma unroll
    for (int a = 0; a < 4; a++) {
        int grow = row0 + rg * 4 + a;
        if (grow < nrows) {
            float o[8];
#pragma unroll
            for (int b = 0; b < 8; b++) {
                float v = acc[a][b];
                if (BIAS) v += bv[b];
                if (RELU) v = fmaxf(v, 0.f);
                o[b] = v;
            }
            *reinterpret_cast<float4*>(&out[(size_t)grow * NOUT + cg * 8]) =
                make_float4(o[0], o[1], o[2], o[3]);
            *reinterpret_cast<float4*>(&out[(size_t)grow * NOUT + cg * 8 + 4]) =
                make_float4(o[4], o[5], o[6], o[7]);
        }
    }
}

// ---------------- launch ----------------

extern "C" void kernel_launch(void* const* d_in, const int* in_sizes, int n_in,
                              void* d_out, int out_size, void* d_ws, size_t ws_size,
                              hipStream_t stream) {
    const float* feat = (const float*)d_in[0]; // [N, 64]
    const float* W1 = (const float*)d_in[1];   // [64, 128]
    const float* b1 = (const float*)d_in[2];
    const float* W2 = (const float*)d_in[3];   // [128, 128]
    const float* b2 = (const float*)d_in[4];
    const float* W3 = (const float*)d_in[5];   // [128, 64]
    const float* b3 = (const float*)d_in[6];
    const int* ei = (const int*)d_in[7];       // [2, E]
    const int* row = ei;
    const int* col = ei + N_EDGES;
    float* out = (float*)d_out;

    // workspace bump allocator (256B aligned)
    char* ws = (char*)d_ws;
    size_t off = 0;
    auto alloc = [&](size_t bytes) {
        void* p = ws + off;
        off = alignUp(off + bytes, 256);
        return p;
    };
    float* B0      = (float*)alloc((size_t)N_NODES * 128 * 4);
    float* B1      = (float*)alloc((size_t)N_NODES * 128 * 4);
    float* dinv    = (float*)alloc((size_t)N_NODES * 4);
    int*   count   = (int*)alloc((size_t)N_NODES * 4);
    int*   offsets = (int*)alloc((size_t)N_NODES * 4);
    int*   cursor  = (int*)alloc((size_t)N_NODES * 4);
    int*   bsum    = (int*)alloc(1024);
    int*   csr_col = (int*)alloc((size_t)N_EDGES * 4);

    const int eb = (N_EDGES + 255) / 256;
    const int gemm_grid = (N_NODES + 63) / 64; // 782

    // CSR build (every call — no cached state allowed)
    k_zero_i32<<<(N_NODES + 255) / 256, 256, 0, stream>>>(count, N_NODES);
    k_count<<<eb, 256, 0, stream>>>(row, count);
    k_blocksum<<<SCAN_BLOCKS, 256, 0, stream>>>(count, bsum);
    k_scan_bsum<<<1, 256, 0, stream>>>(bsum);
    k_scan_final<<<SCAN_BLOCKS, 256, 0, stream>>>(count, bsum, offsets, cursor, dinv);
    k_scatter<<<eb, 256, 0, stream>>>(row, col, cursor, csr_col);

    // Layer 1: aggregate at F=64 first (A@X)W1, then GEMM+bias+relu
    k_aggregate<64, false><<<N_NODES / 4, 256, 0, stream>>>(feat, B0, csr_col, offsets, count, dinv, nullptr);
    k_gemm<64, 128, true, true><<<gemm_grid, 256, 0, stream>>>(B0, W1, b1, B1, N_NODES);

    // Layer 2: aggregate at F=128, then GEMM+bias+relu
    k_aggregate<128, false><<<N_NODES / 2, 256, 0, stream>>>(B1, B0, csr_col, offsets, count, dinv, nullptr);
    k_gemm<128, 128, true, true><<<gemm_grid, 256, 0, stream>>>(B0, W2, b2, B1, N_NODES);

    // Layer 3: transform first (F_out=64), then aggregate + bias (no relu)
    k_gemm<128, 64, false, false><<<gemm_grid, 128, 0, stream>>>(B1, W3, nullptr, B0, N_NODES);
    k_aggregate<64, true><<<N_NODES / 4, 256, 0, stream>>>(B0, out, csr_col, offsets, count, dinv, b3);
}

// Round 2
// 329.730 us; speedup vs baseline: 1.1106x; 1.1106x over previous
//
#include <hip/hip_runtime.h>

#define N_NODES 50000
#define N_EDGES 800000

#define SCAN_CHUNK 256
#define SCAN_BLOCKS ((N_NODES + SCAN_CHUNK - 1) / SCAN_CHUNK) // 196

static inline size_t alignUp(size_t x, size_t a) { return (x + a - 1) & ~(a - 1); }

// ---------------- CSR build ----------------

__global__ void k_zero_i32(int* __restrict__ p, int n) {
    int i = blockIdx.x * 256 + threadIdx.x;
    if (i < n) p[i] = 0;
}

__global__ void k_count(const int* __restrict__ row, int* __restrict__ count) {
    int e = blockIdx.x * 256 + threadIdx.x;
    if (e < N_EDGES) atomicAdd(&count[row[e]], 1);
}

__global__ void k_blocksum(const int* __restrict__ count, int* __restrict__ bsum) {
    __shared__ int s[256];
    int t = threadIdx.x;
    int i = blockIdx.x * 256 + t;
    int v = (i < N_NODES) ? count[i] : 0;
    s[t] = v;
    __syncthreads();
    for (int off = 128; off > 0; off >>= 1) {
        if (t < off) s[t] += s[t + off];
        __syncthreads();
    }
    if (t == 0) bsum[blockIdx.x] = s[0];
}

__global__ void k_scan_bsum(int* __restrict__ bsum) {
    __shared__ int s[256];
    int t = threadIdx.x;
    int v = (t < SCAN_BLOCKS) ? bsum[t] : 0;
    s[t] = v;
    __syncthreads();
    for (int off = 1; off < 256; off <<= 1) {
        int add = (t >= off) ? s[t - off] : 0;
        __syncthreads();
        s[t] += add;
        __syncthreads();
    }
    if (t < SCAN_BLOCKS) bsum[t] = s[t] - v; // exclusive
}

__global__ void k_scan_final(const int* __restrict__ count, const int* __restrict__ bsum,
                             int* __restrict__ offsets, int* __restrict__ cursor,
                             float* __restrict__ dinv) {
    __shared__ int s[256];
    int t = threadIdx.x;
    int i = blockIdx.x * 256 + t;
    int v = (i < N_NODES) ? count[i] : 0;
    s[t] = v;
    __syncthreads();
    for (int off = 1; off < 256; off <<= 1) {
        int add = (t >= off) ? s[t - off] : 0;
        __syncthreads();
        s[t] += add;
        __syncthreads();
    }
    if (i < N_NODES) {
        int excl = s[t] - v + bsum[blockIdx.x];
        offsets[i] = excl;
        cursor[i]  = excl;
        dinv[i]    = rsqrtf((float)(v + 1)); // +1 self-loop; always > 0
    }
}

__global__ void k_scatter(const int* __restrict__ row, const int* __restrict__ col,
                          int* __restrict__ cursor, int* __restrict__ csr_col) {
    int e = blockIdx.x * 256 + threadIdx.x;
    if (e < N_EDGES) {
        int r = row[e];
        int pos = atomicAdd(&cursor[r], 1);
        csr_col[pos] = col[e];
    }
}

// ---------------- prescale: o[i,:] = dinv[i] * f[i,:]  (F=64, float4 grain) ----

__global__ void k_prescale64(const float* __restrict__ f, const float* __restrict__ dinv,
                             float* __restrict__ o) {
    int i = blockIdx.x * 256 + threadIdx.x; // float4 index
    if (i < N_NODES * 16) {
        int node = i >> 4;
        float d = dinv[node];
        float4 v = reinterpret_cast<const float4*>(f)[i];
        reinterpret_cast<float4*>(o)[i] = make_float4(v.x * d, v.y * d, v.z * d, v.w * d);
    }
}

// ---------------- Aggregation over PRE-SCALED rows ----------------
// out[i] = dinv_i * ( h'[i] + sum_c h'[c] ) (+bias), h' = dinv .* h
// float2 per lane, 8-way unrolled independent gathers for MLP.

template <int F, bool BIAS>
__global__ void k_aggregate(const float* __restrict__ hs, float* __restrict__ out,
                            const int* __restrict__ csr_col, const int* __restrict__ offsets,
                            const int* __restrict__ count, const float* __restrict__ dinv,
                            const float* __restrict__ bias) {
    constexpr int L = F / 2;        // lanes per node (float2 per lane)
    constexpr int NPB = 256 / L;    // nodes per block
    int node = blockIdx.x * NPB + threadIdx.x / L;
    int f2 = threadIdx.x % L;
    if (node >= N_NODES) return;

    const float2* h2 = reinterpret_cast<const float2*>(hs);
    float sx[8], sy[8];
#pragma unroll
    for (int u = 0; u < 8; u++) { sx[u] = 0.f; sy[u] = 0.f; }
    float2 self = h2[(size_t)node * L + f2];
    sx[0] = self.x; sy[0] = self.y;

    int n = count[node];
    const int* cp = csr_col + offsets[node];

    int e = 0;
    for (; e + 8 <= n; e += 8) {
        int c[8];
#pragma unroll
        for (int u = 0; u < 8; u++) c[u] = cp[e + u];
#pragma unroll
        for (int u = 0; u < 8; u++) {
            float2 v = h2[(size_t)c[u] * L + f2];
            sx[u] += v.x; sy[u] += v.y;
        }
    }
    for (; e + 2 <= n; e += 2) {
        int c0 = cp[e], c1 = cp[e + 1];
        float2 v0 = h2[(size_t)c0 * L + f2];
        float2 v1 = h2[(size_t)c1 * L + f2];
        sx[0] += v0.x; sy[0] += v0.y;
        sx[1] += v1.x; sy[1] += v1.y;
    }
    if (e < n) {
        int c = cp[e];
        float2 v = h2[(size_t)c * L + f2];
        sx[0] += v.x; sy[0] += v.y;
    }

    float ox = 0.f, oy = 0.f;
#pragma unroll
    for (int u = 0; u < 8; u++) { ox += sx[u]; oy += sy[u]; }
    float di = dinv[node];
    ox *= di; oy *= di;
    if (BIAS) { ox += bias[2 * f2]; oy += bias[2 * f2 + 1]; }
    reinterpret_cast<float2*>(out)[(size_t)node * L + f2] = make_float2(ox, oy);
}

// ---------------- fp32 GEMM, 8xNCOLS micro-tile, BM=128, BK=32 ----------------
// out[r,c] = post( x[r,:] @ W[:,c] ), post = (+bias) -> relu -> (*dinv[r])
// xt is the x-tile TRANSPOSED [k][r] with XOR swizzle on r (2-way max conflicts).

template <int K, int NOUT, int NCOLS, bool RELU, bool BIAS, bool SCALE>
__global__ void k_gemm(const float* __restrict__ x, const float* __restrict__ W,
                       const float* __restrict__ bias, const float* __restrict__ dinv,
                       float* __restrict__ out, int nrows) {
    constexpr int BM = 128, BK = 32;
    static_assert(NOUT / NCOLS == 16, "cg must be tid>>4");
    __shared__ float xt[BK * BM];    // swizzled transposed x tile (16 KB)
    __shared__ float wt[BK * NOUT];  // W tile

    int tid = threadIdx.x;
    int rg = tid & 15;   // 16 row groups: rows rg*4+{0..3} and rg*4+64+{0..3}
    int cg = tid >> 4;   // 16 col groups of NCOLS
    int row0 = blockIdx.x * BM;

    float acc[8][NCOLS] = {};

    for (int kk = 0; kk < K; kk += BK) {
        __syncthreads();
        // ---- x tile: 128 rows x 32 k, coalesced float4 loads, swizzled transpose store
#pragma unroll
        for (int t = 0; t < (BM * BK / 4) / 256; ++t) {
            int idx = tid + t * 256;
            int r = idx >> 3;
            int kc = (idx & 7) * 4;
            float4 v = make_float4(0.f, 0.f, 0.f, 0.f);
            int gr = row0 + r;
            if (gr < nrows) v = *reinterpret_cast<const float4*>(&x[(size_t)gr * K + kk + kc]);
            int s = ((kc >> 2) & 7) << 2; // (kc+j)>>2 == kc>>2 for j<4
            xt[(kc + 0) * BM + (r ^ s)] = v.x;
            xt[(kc + 1) * BM + (r ^ s)] = v.y;
            xt[(kc + 2) * BM + (r ^ s)] = v.z;
            xt[(kc + 3) * BM + (r ^ s)] = v.w;
        }
        // ---- W tile: 32 k x NOUT
#pragma unroll
        for (int t = 0; t < (BK * NOUT / 4) / 256; ++t) {
            int idx = tid + t * 256;
            int k = idx / (NOUT / 4);
            int c = (idx % (NOUT / 4)) * 4;
            *reinterpret_cast<float4*>(&wt[k * NOUT + c]) =
                *reinterpret_cast<const float4*>(&W[(size_t)(kk + k) * NOUT + c]);
        }
        __syncthreads();

#pragma unroll
        for (int k = 0; k < BK; ++k) {
            int s = ((k >> 2) & 7) << 2;
            float4 x0 = *reinterpret_cast<const float4*>(&xt[k * BM + ((rg * 4) ^ s)]);
            float4 x1 = *reinterpret_cast<const float4*>(&xt[k * BM + (((rg * 4) ^ s) + 64)]);
            float xr[8] = {x0.x, x0.y, x0.z, x0.w, x1.x, x1.y, x1.z, x1.w};
            float wr[NCOLS];
            float4 w0 = *reinterpret_cast<const float4*>(&wt[k * NOUT + cg * NCOLS]);
            wr[0] = w0.x; wr[1] = w0.y; wr[2] = w0.z; wr[3] = w0.w;
            if (NCOLS == 8) {
                float4 w1 = *reinterpret_cast<const float4*>(&wt[k * NOUT + cg * NCOLS + 4]);
                wr[4] = w1.x; wr[5] = w1.y; wr[6] = w1.z; wr[7] = w1.w;
            }
#pragma unroll
            for (int a = 0; a < 8; a++)
#pragma unroll
                for (int b = 0; b < NCOLS; b++) acc[a][b] += xr[a] * wr[b];
        }
    }

    float bv[NCOLS];
    if (BIAS) {
#pragma unroll
        for (int b = 0; b < NCOLS; b++) bv[b] = bias[cg * NCOLS + b];
    }
#pragma unroll
    for (int a = 0; a < 8; a++) {
        int r = rg * 4 + (a & 3) + ((a >= 4) ? 64 : 0);
        int gr = row0 + r;
        if (gr >= nrows) continue;
        float d = SCALE ? dinv[gr] : 1.f;
        float o[NCOLS];
#pragma unroll
        for (int b = 0; b < NCOLS; b++) {
            float v = acc[a][b];
            if (BIAS) v += bv[b];
            if (RELU) v = fmaxf(v, 0.f);
            o[b] = v * d;
        }
        *reinterpret_cast<float4*>(&out[(size_t)gr * NOUT + cg * NCOLS]) =
            make_float4(o[0], o[1], o[2], o[3]);
        if (NCOLS == 8)
            *reinterpret_cast<float4*>(&out[(size_t)gr * NOUT + cg * NCOLS + 4]) =
                make_float4(o[4], o[5], o[6], o[7]);
    }
}

// ---------------- launch ----------------

extern "C" void kernel_launch(void* const* d_in, const int* in_sizes, int n_in,
                              void* d_out, int out_size, void* d_ws, size_t ws_size,
                              hipStream_t stream) {
    const float* feat = (const float*)d_in[0]; // [N, 64]
    const float* W1 = (const float*)d_in[1];   // [64, 128]
    const float* b1 = (const float*)d_in[2];
    const float* W2 = (const float*)d_in[3];   // [128, 128]
    const float* b2 = (const float*)d_in[4];
    const float* W3 = (const float*)d_in[5];   // [128, 64]
    const float* b3 = (const float*)d_in[6];
    const int* ei = (const int*)d_in[7];       // [2, E]
    const int* row = ei;
    const int* col = ei + N_EDGES;
    float* out = (float*)d_out;

    // workspace bump allocator (256B aligned)
    char* ws = (char*)d_ws;
    size_t off = 0;
    auto alloc = [&](size_t bytes) {
        void* p = ws + off;
        off = alignUp(off + bytes, 256);
        return p;
    };
    float* B0      = (float*)alloc((size_t)N_NODES * 128 * 4);
    float* B1      = (float*)alloc((size_t)N_NODES * 128 * 4);
    float* dinv    = (float*)alloc((size_t)N_NODES * 4);
    int*   count   = (int*)alloc((size_t)N_NODES * 4);
    int*   offsets = (int*)alloc((size_t)N_NODES * 4);
    int*   cursor  = (int*)alloc((size_t)N_NODES * 4);
    int*   bsum    = (int*)alloc(1024);
    int*   csr_col = (int*)alloc((size_t)N_EDGES * 4);
    // featS (N x 64) overlays B1: dead before GEMM1 writes B1.
    float* featS   = B1;

    const int eb = (N_EDGES + 255) / 256;
    const int gemm_grid = (N_NODES + 127) / 128; // 391

    // CSR build (every call — no cached state allowed)
    k_zero_i32<<<(N_NODES + 255) / 256, 256, 0, stream>>>(count, N_NODES);
    k_count<<<eb, 256, 0, stream>>>(row, count);
    k_blocksum<<<SCAN_BLOCKS, 256, 0, stream>>>(count, bsum);
    k_scan_bsum<<<1, 256, 0, stream>>>(bsum);
    k_scan_final<<<SCAN_BLOCKS, 256, 0, stream>>>(count, bsum, offsets, cursor, dinv);
    k_scatter<<<eb, 256, 0, stream>>>(row, col, cursor, csr_col);

    // features pre-scaled by dinv (so aggregate gathers need no dinv[c])
    k_prescale64<<<(N_NODES * 16 + 255) / 256, 256, 0, stream>>>(feat, dinv, featS);

    // Layer 1: agg1 = A_hat@feat (F=64), then x1' = dinv .* relu(agg1@W1+b1)
    k_aggregate<64, false><<<N_NODES / 8, 256, 0, stream>>>(featS, B0, csr_col, offsets, count, dinv, nullptr);
    k_gemm<64, 128, 8, true, true, true><<<gemm_grid, 256, 0, stream>>>(B0, W1, b1, dinv, B1, N_NODES);

    // Layer 2: agg2 = A_hat@x1 (F=128), then x2 = relu(agg2@W2+b2) (unscaled)
    k_aggregate<128, false><<<N_NODES / 4, 256, 0, stream>>>(B1, B0, csr_col, offsets, count, dinv, nullptr);
    k_gemm<128, 128, 8, true, true, false><<<gemm_grid, 256, 0, stream>>>(B0, W2, b2, dinv, B1, N_NODES);

    // Layer 3: h3' = dinv .* (x2@W3), then out = A_hat-agg + b3
    k_gemm<128, 64, 4, false, false, true><<<gemm_grid, 256, 0, stream>>>(B1, W3, nullptr, dinv, B0, N_NODES);
    k_aggregate<64, true><<<N_NODES / 8, 256, 0, stream>>>(B0, out, csr_col, offsets, count, dinv, b3);
}